// Round 1
// baseline (618.747 us; speedup 1.0000x reference)
//
#include <hip/hip_runtime.h>
#include <hip/hip_bf16.h>
#include <math.h>

// Problem constants
#define BB 256
#define TT 256
#define EE 384
#define HH 6
#define DD 64

typedef __attribute__((ext_vector_type(8))) short bf16x8;
typedef __attribute__((ext_vector_type(4))) float f32x4;

__device__ inline unsigned short f2bf(float f) {
  // round-to-nearest-even fp32 -> bf16 (no NaNs expected in this pipeline)
  unsigned int u = __builtin_bit_cast(unsigned int, f);
  u += 0x7fffu + ((u >> 16) & 1u);
  return (unsigned short)(u >> 16);
}

// ---------------------------------------------------------------------------
// Kernel 0: fp32 -> bf16 convert (x -> xb)
// ---------------------------------------------------------------------------
__global__ __launch_bounds__(256) void cvt_kernel(const float* __restrict__ x,
                                                  unsigned short* __restrict__ xb,
                                                  int n4) {
  int i = blockIdx.x * 256 + threadIdx.x;
  if (i < n4) {
    float4 f = ((const float4*)x)[i];
    ushort4 o;
    o.x = f2bf(f.x); o.y = f2bf(f.y); o.z = f2bf(f.z); o.w = f2bf(f.w);
    ((ushort4*)xb)[i] = o;
  }
}

// ---------------------------------------------------------------------------
// Kernel 1: QKV projection.  For each (mat, head): C[M=65536,64] = xb @ W[h]
// q,k stored [B,H,T,D]; v stored transposed [B,H,D,T] (LDS bounce).
// ---------------------------------------------------------------------------
__global__ __launch_bounds__(256) void qkv_kernel(const unsigned short* __restrict__ xb,
                                                  const float* __restrict__ Wq,
                                                  const float* __restrict__ Wk,
                                                  const float* __restrict__ Wv,
                                                  unsigned short* __restrict__ q,
                                                  unsigned short* __restrict__ k,
                                                  unsigned short* __restrict__ v) {
  const int m0  = blockIdx.x * 64;        // token-tile base (within b: all rows same b)
  const int mat = blockIdx.y / HH;        // 0=q 1=k 2=v
  const int h   = blockIdx.y % HH;
  const float* W = (mat == 0 ? Wq : (mat == 1 ? Wk : Wv)) + (size_t)h * EE * DD;

  __shared__ unsigned short As[64 * 32];
  __shared__ unsigned short Bs[64 * 32];
  __shared__ unsigned short Ct[64 * 72];  // V-transpose bounce (pad 8 vs bank conflicts)

  const int tid = threadIdx.x;
  const int wave = tid >> 6, lane = tid & 63;
  const int l15 = lane & 15, quad = lane >> 4;

  f32x4 acc[4] = {{0.f,0.f,0.f,0.f},{0.f,0.f,0.f,0.f},{0.f,0.f,0.f,0.f},{0.f,0.f,0.f,0.f}};

  for (int k0 = 0; k0 < EE; k0 += 32) {
    __syncthreads();
    // stage A tile [64 rows][32 k] bf16 (coalesced 16B)
    {
      int r = tid >> 2, c = (tid & 3) * 8;
      const unsigned short* src = xb + (size_t)(m0 + r) * EE + k0 + c;
      *(uint4*)&As[r * 32 + c] = *(const uint4*)src;
    }
    // stage B^T tile Bs[n][kk] from W[k0+kk][n]  (fp32 -> bf16)
    {
      int kk = tid >> 3, n8 = (tid & 7) * 8;
      const float* src = W + (size_t)(k0 + kk) * DD + n8;
      float4 f0 = *(const float4*)src;
      float4 f1 = *(const float4*)(src + 4);
      float tmp[8] = {f0.x, f0.y, f0.z, f0.w, f1.x, f1.y, f1.z, f1.w};
#pragma unroll
      for (int i = 0; i < 8; ++i) Bs[(n8 + i) * 32 + kk] = f2bf(tmp[i]);
    }
    __syncthreads();
    // MFMA: each wave does 16 rows x 64 cols
    bf16x8 a = *(const bf16x8*)&As[(wave * 16 + l15) * 32 + quad * 8];
#pragma unroll
    for (int ct = 0; ct < 4; ++ct) {
      bf16x8 b = *(const bf16x8*)&Bs[(ct * 16 + l15) * 32 + quad * 8];
      acc[ct] = __builtin_amdgcn_mfma_f32_16x16x32_bf16(a, b, acc[ct], 0, 0, 0);
    }
  }

  const int b  = m0 >> 8;       // T=256 rows per batch; 64-row tile stays in one b
  const int t0 = m0 & 255;
  if (mat != 2) {
    unsigned short* outp = (mat == 0) ? q : k;
#pragma unroll
    for (int ct = 0; ct < 4; ++ct) {
#pragma unroll
      for (int r = 0; r < 4; ++r) {
        int row = wave * 16 + quad * 4 + r;           // local token
        int col = ct * 16 + l15;                       // d
        outp[(((size_t)b * HH + h) * TT + t0 + row) * DD + col] = f2bf(acc[ct][r]);
      }
    }
  } else {
    // transpose C tile via LDS, then coalesced store into v[B,H,D,T]
#pragma unroll
    for (int ct = 0; ct < 4; ++ct) {
#pragma unroll
      for (int r = 0; r < 4; ++r) {
        int row = wave * 16 + quad * 4 + r;
        int col = ct * 16 + l15;
        Ct[col * 72 + row] = f2bf(acc[ct][r]);
      }
    }
    __syncthreads();
    int d = tid >> 2, c = (tid & 3) * 16;
    unsigned short* dst = v + (((size_t)b * HH + h) * DD + d) * TT + t0 + c;
    *(uint4*)dst       = *(const uint4*)&Ct[d * 72 + c];
    *(uint4*)(dst + 8) = *(const uint4*)&Ct[d * 72 + c + 8];
  }
}

// ---------------------------------------------------------------------------
// Kernel 2: flash-style causal attention.
// block = (b,h, 64-row Q tile); loops over 64-key tiles up to diagonal.
// q,k: [B,H,T,D]; v: [B,H,D,T]; att out: [B,T,H,D] bf16.
// ---------------------------------------------------------------------------
__global__ __launch_bounds__(256) void attn_kernel(const unsigned short* __restrict__ q,
                                                   const unsigned short* __restrict__ k,
                                                   const unsigned short* __restrict__ v,
                                                   unsigned short* __restrict__ att) {
  const int bh = blockIdx.x;           // b*H + h
  const int q0 = blockIdx.y * 64;
  const int b = bh / HH, h = bh % HH;

  __shared__ unsigned short Qs[64 * 72];
  __shared__ unsigned short Ks[64 * 72];
  __shared__ unsigned short Vt[64 * 72];   // [d][key]
  __shared__ unsigned short Ps[64 * 72];

  const int tid = threadIdx.x;
  const int wave = tid >> 6, lane = tid & 63;
  const int l15 = lane & 15, quad = lane >> 4;
  const int koff = quad * 8;

  // load Q tile (64 x 64)
  {
    int r = tid >> 2, c = (tid & 3) * 16;
    const unsigned short* src = q + ((size_t)bh * TT + q0 + r) * DD + c;
    *(uint4*)&Qs[r * 72 + c]     = *(const uint4*)src;
    *(uint4*)&Qs[r * 72 + c + 8] = *(const uint4*)(src + 8);
  }

  f32x4 o_acc[4] = {{0.f,0.f,0.f,0.f},{0.f,0.f,0.f,0.f},{0.f,0.f,0.f,0.f},{0.f,0.f,0.f,0.f}};
  float m_run[4] = {-INFINITY, -INFINITY, -INFINITY, -INFINITY};
  float l_run[4] = {0.f, 0.f, 0.f, 0.f};

  const float scale = 0.125f;  // 1/sqrt(64)

  for (int j0 = 0; j0 <= q0; j0 += 64) {
    __syncthreads();
    // stage K tile [key][d] and V^T tile [d][key]
    {
      int r = tid >> 2, c = (tid & 3) * 16;
      const unsigned short* ks = k + ((size_t)bh * TT + j0 + r) * DD + c;
      *(uint4*)&Ks[r * 72 + c]     = *(const uint4*)ks;
      *(uint4*)&Ks[r * 72 + c + 8] = *(const uint4*)(ks + 8);
      const unsigned short* vs = v + ((size_t)bh * DD + r) * TT + j0 + c;
      *(uint4*)&Vt[r * 72 + c]     = *(const uint4*)vs;
      *(uint4*)&Vt[r * 72 + c + 8] = *(const uint4*)(vs + 8);
    }
    __syncthreads();

    // S = Q K^T for this wave's 16 q rows x 64 keys
    f32x4 s_acc[4] = {{0.f,0.f,0.f,0.f},{0.f,0.f,0.f,0.f},{0.f,0.f,0.f,0.f},{0.f,0.f,0.f,0.f}};
#pragma unroll
    for (int kc = 0; kc < 2; ++kc) {
      bf16x8 a = *(const bf16x8*)&Qs[(wave * 16 + l15) * 72 + kc * 32 + koff];
#pragma unroll
      for (int ct = 0; ct < 4; ++ct) {
        bf16x8 bb = *(const bf16x8*)&Ks[(ct * 16 + l15) * 72 + kc * 32 + koff];
        s_acc[ct] = __builtin_amdgcn_mfma_f32_16x16x32_bf16(a, bb, s_acc[ct], 0, 0, 0);
      }
    }

    const bool diag = (j0 == q0);
    const int rowbase = q0 + wave * 16 + quad * 4;
#pragma unroll
    for (int r = 0; r < 4; ++r) {
      int qrow = rowbase + r;
      float sv[4];
#pragma unroll
      for (int ct = 0; ct < 4; ++ct) {
        float s = s_acc[ct][r] * scale;
        if (diag && (j0 + ct * 16 + l15) > qrow) s = -INFINITY;
        sv[ct] = s;
      }
      float mt = fmaxf(fmaxf(sv[0], sv[1]), fmaxf(sv[2], sv[3]));
      mt = fmaxf(mt, __shfl_xor(mt, 1));
      mt = fmaxf(mt, __shfl_xor(mt, 2));
      mt = fmaxf(mt, __shfl_xor(mt, 4));
      mt = fmaxf(mt, __shfl_xor(mt, 8));
      float mnew = fmaxf(m_run[r], mt);
      float alpha = __expf(m_run[r] - mnew);
      float psum = 0.f;
      int prow = (wave * 16 + quad * 4 + r) * 72;
#pragma unroll
      for (int ct = 0; ct < 4; ++ct) {
        float p = __expf(sv[ct] - mnew);
        psum += p;
        Ps[prow + ct * 16 + l15] = f2bf(p);
      }
      psum += __shfl_xor(psum, 1);
      psum += __shfl_xor(psum, 2);
      psum += __shfl_xor(psum, 4);
      psum += __shfl_xor(psum, 8);
      l_run[r] = l_run[r] * alpha + psum;
      m_run[r] = mnew;
#pragma unroll
      for (int dt = 0; dt < 4; ++dt) o_acc[dt][r] *= alpha;
    }

    // O += P @ V   (Ps written/read only by this wave's own rows -> no barrier)
#pragma unroll
    for (int kc = 0; kc < 2; ++kc) {
      bf16x8 a = *(const bf16x8*)&Ps[(wave * 16 + l15) * 72 + kc * 32 + koff];
#pragma unroll
      for (int dt = 0; dt < 4; ++dt) {
        bf16x8 bb = *(const bf16x8*)&Vt[(dt * 16 + l15) * 72 + kc * 32 + koff];
        o_acc[dt] = __builtin_amdgcn_mfma_f32_16x16x32_bf16(a, bb, o_acc[dt], 0, 0, 0);
      }
    }
  }

  // epilogue: O /= l, store att[B,T,H,D]
#pragma unroll
  for (int dt = 0; dt < 4; ++dt) {
#pragma unroll
    for (int r = 0; r < 4; ++r) {
      int row = wave * 16 + quad * 4 + r;
      int t = q0 + row;
      int d = dt * 16 + l15;
      float o = o_acc[dt][r] / l_run[r];
      att[(((size_t)b * TT + t) * HH + h) * DD + d] = f2bf(o);
    }
  }
}

// ---------------------------------------------------------------------------
// Kernel 3: output projection  out[M,384] = att[M,384] @ Wo[384,384] + bo  (fp32 out)
// ---------------------------------------------------------------------------
__global__ __launch_bounds__(256) void oproj_kernel(const unsigned short* __restrict__ att,
                                                    const float* __restrict__ Wo,
                                                    const float* __restrict__ bo,
                                                    float* __restrict__ out) {
  const int m0 = blockIdx.x * 64;
  const int n0 = blockIdx.y * 64;

  __shared__ unsigned short As[64 * 32];
  __shared__ unsigned short Bs[64 * 32];

  const int tid = threadIdx.x;
  const int wave = tid >> 6, lane = tid & 63;
  const int l15 = lane & 15, quad = lane >> 4;

  f32x4 acc[4] = {{0.f,0.f,0.f,0.f},{0.f,0.f,0.f,0.f},{0.f,0.f,0.f,0.f},{0.f,0.f,0.f,0.f}};

  for (int k0 = 0; k0 < EE; k0 += 32) {
    __syncthreads();
    {
      int r = tid >> 2, c = (tid & 3) * 8;
      const unsigned short* src = att + (size_t)(m0 + r) * EE + k0 + c;
      *(uint4*)&As[r * 32 + c] = *(const uint4*)src;
    }
    {
      int kk = tid >> 3, n8 = (tid & 7) * 8;
      const float* src = Wo + (size_t)(k0 + kk) * EE + n0 + n8;
      float4 f0 = *(const float4*)src;
      float4 f1 = *(const float4*)(src + 4);
      float tmp[8] = {f0.x, f0.y, f0.z, f0.w, f1.x, f1.y, f1.z, f1.w};
#pragma unroll
      for (int i = 0; i < 8; ++i) Bs[(n8 + i) * 32 + kk] = f2bf(tmp[i]);
    }
    __syncthreads();
    bf16x8 a = *(const bf16x8*)&As[(wave * 16 + l15) * 32 + quad * 8];
#pragma unroll
    for (int ct = 0; ct < 4; ++ct) {
      bf16x8 b = *(const bf16x8*)&Bs[(ct * 16 + l15) * 32 + quad * 8];
      acc[ct] = __builtin_amdgcn_mfma_f32_16x16x32_bf16(a, b, acc[ct], 0, 0, 0);
    }
  }

#pragma unroll
  for (int ct = 0; ct < 4; ++ct) {
    int col = n0 + ct * 16 + l15;
    float bias = bo[col];
#pragma unroll
    for (int r = 0; r < 4; ++r) {
      int row = m0 + wave * 16 + quad * 4 + r;
      out[(size_t)row * EE + col] = acc[ct][r] + bias;
    }
  }
}

// ---------------------------------------------------------------------------
extern "C" void kernel_launch(void* const* d_in, const int* in_sizes, int n_in,
                              void* d_out, int out_size, void* d_ws, size_t ws_size,
                              hipStream_t stream) {
  const float* x  = (const float*)d_in[0];
  const float* Wq = (const float*)d_in[1];
  const float* Wk = (const float*)d_in[2];
  const float* Wv = (const float*)d_in[3];
  const float* Wo = (const float*)d_in[4];
  const float* bo = (const float*)d_in[5];
  float* out = (float*)d_out;

  char* ws = (char*)d_ws;
  const size_t SZ = (size_t)BB * TT * EE * 2;       // 50,331,648 B
  const size_t SQ = (size_t)BB * HH * TT * DD * 2;  // 50,331,648 B
  unsigned short* xb = (unsigned short*)ws;          // [B*T, E] bf16
  unsigned short* q  = (unsigned short*)(ws + SZ);
  unsigned short* k  = (unsigned short*)(ws + SZ + SQ);
  unsigned short* v  = (unsigned short*)(ws + SZ + 2 * SQ);
  unsigned short* att = xb;  // xb dead after qkv_kernel; reuse as attention output

  int n4 = (BB * TT * EE) / 4;
  cvt_kernel<<<(n4 + 255) / 256, 256, 0, stream>>>(x, xb, n4);
  qkv_kernel<<<dim3((BB * TT) / 64, 3 * HH), 256, 0, stream>>>(xb, Wq, Wk, Wv, q, k, v);
  attn_kernel<<<dim3(BB * HH, TT / 64), 256, 0, stream>>>(q, k, v, att);
  oproj_kernel<<<dim3((BB * TT) / 64, EE / 64), 256, 0, stream>>>(att, Wo, bo, out);
}

// Round 2
// 398.061 us; speedup vs baseline: 1.5544x; 1.5544x over previous
//
#include <hip/hip_runtime.h>
#include <hip/hip_bf16.h>
#include <math.h>

// Problem constants
#define BB 256
#define TT 256
#define EE 384
#define HH 6
#define DD 64

typedef __attribute__((ext_vector_type(8))) short bf16x8;
typedef __attribute__((ext_vector_type(4))) float f32x4;

__device__ inline unsigned short f2bf(float f) {
  unsigned int u = __builtin_bit_cast(unsigned int, f);
  u += 0x7fffu + ((u >> 16) & 1u);
  return (unsigned short)(u >> 16);
}

__device__ __forceinline__ void g2l16(const unsigned short* g, unsigned short* l) {
  // async global -> LDS, 16B per lane; LDS dest = wave-uniform base + lane*16
  __builtin_amdgcn_global_load_lds(
      (const __attribute__((address_space(1))) void*)g,
      (__attribute__((address_space(3))) void*)l, 16, 0, 0);
}

// ---------------------------------------------------------------------------
// Kernel 0: fp32 -> bf16 convert (x -> xb)
// ---------------------------------------------------------------------------
__global__ __launch_bounds__(256) void cvt_kernel(const float* __restrict__ x,
                                                  unsigned short* __restrict__ xb,
                                                  int n4) {
  int i = blockIdx.x * 256 + threadIdx.x;
  if (i < n4) {
    float4 f = ((const float4*)x)[i];
    ushort4 o;
    o.x = f2bf(f.x); o.y = f2bf(f.y); o.z = f2bf(f.z); o.w = f2bf(f.w);
    ((ushort4*)xb)[i] = o;
  }
}

// ---------------------------------------------------------------------------
// Kernel 0b: weight prep. Wt[1536][384] bf16:
//   rows 0..1151:  Wt[mat*384 + h*64 + d][e] = W{q,k,v}[h][e][d]
//   rows 1152..1535: Wt[1152 + n][k] = Wo[k][n]
// ---------------------------------------------------------------------------
__global__ __launch_bounds__(256) void wprep_kernel(const float* __restrict__ Wq,
                                                    const float* __restrict__ Wk,
                                                    const float* __restrict__ Wv,
                                                    const float* __restrict__ Wo,
                                                    unsigned short* __restrict__ Wt) {
  int idx = blockIdx.x * 256 + threadIdx.x;
  if (idx >= 1536 * 384) return;
  int n = idx / 384, k = idx % 384;
  float val;
  if (n < 1152) {
    int mat = n / 384;
    int c = n % 384;
    int h = c >> 6, d = c & 63;
    const float* W = (mat == 0) ? Wq : (mat == 1 ? Wk : Wv);
    val = W[((size_t)h * EE + k) * DD + d];
  } else {
    int c = n - 1152;
    val = Wo[(size_t)k * EE + c];
  }
  Wt[idx] = f2bf(val);
}

// ---------------------------------------------------------------------------
// Kernel 1: fused QKV GEMM.  C[65536, 1152] = xb @ [Wq|Wk|Wv]  (bf16 MFMA)
// 128x128 tile, BK=64, global_load_lds(16B) staging, XOR-swizzled LDS.
// n-tiles 0..2 -> q [B,H,T,D]; 3..5 -> k; 6..8 -> v transposed [B,H,D,T].
// ---------------------------------------------------------------------------
__global__ __launch_bounds__(256) void qkv128_kernel(const unsigned short* __restrict__ A,
                                                     const unsigned short* __restrict__ Wt,
                                                     unsigned short* __restrict__ q,
                                                     unsigned short* __restrict__ k,
                                                     unsigned short* __restrict__ v) {
  const int bx = blockIdx.x;            // n-tile (0..8)
  const int m0 = blockIdx.y * 128;
  const int n0 = bx * 128;

  __shared__ char smem[32768];
  unsigned short* As = (unsigned short*)smem;            // [128][64] swizzled
  unsigned short* Bs = (unsigned short*)(smem + 16384);  // [128][64] swizzled
  unsigned short* bounce = (unsigned short*)smem;        // [64][136] after mainloop

  const int tid = threadIdx.x;
  const int wave = tid >> 6, lane = tid & 63;
  const int l15 = lane & 15, quad = lane >> 4;
  const int wm = (wave & 1) * 64, wn = (wave >> 1) * 64;
  const int xs = l15 & 7;

  f32x4 acc[4][4];
#pragma unroll
  for (int i = 0; i < 4; ++i)
#pragma unroll
    for (int j = 0; j < 4; ++j) acc[i][j] = (f32x4){0.f, 0.f, 0.f, 0.f};

  const int rl_base = wave * 32 + (lane >> 3);
  const int sb = lane & 7;

  for (int k0 = 0; k0 < EE; k0 += 64) {
    __syncthreads();
#pragma unroll
    for (int i = 0; i < 4; ++i) {
      int rl = rl_base + i * 8;
      int gcb = sb ^ (rl & 7);
      g2l16(A + (size_t)(m0 + rl) * EE + k0 + gcb * 8, &As[(wave * 32 + i * 8) * 64]);
    }
#pragma unroll
    for (int i = 0; i < 4; ++i) {
      int rl = rl_base + i * 8;
      int gcb = sb ^ (rl & 7);
      g2l16(Wt + (size_t)(n0 + rl) * EE + k0 + gcb * 8, &Bs[(wave * 32 + i * 8) * 64]);
    }
    __syncthreads();
#pragma unroll
    for (int kc = 0; kc < 2; ++kc) {
      bf16x8 af[4], bfr[4];
#pragma unroll
      for (int mi = 0; mi < 4; ++mi)
        af[mi] = *(const bf16x8*)&As[(wm + mi * 16 + l15) * 64 + ((kc * 4 + quad) ^ xs) * 8];
#pragma unroll
      for (int ni = 0; ni < 4; ++ni)
        bfr[ni] = *(const bf16x8*)&Bs[(wn + ni * 16 + l15) * 64 + ((kc * 4 + quad) ^ xs) * 8];
#pragma unroll
      for (int mi = 0; mi < 4; ++mi)
#pragma unroll
        for (int ni = 0; ni < 4; ++ni)
          acc[mi][ni] = __builtin_amdgcn_mfma_f32_16x16x32_bf16(af[mi], bfr[ni], acc[mi][ni], 0, 0, 0);
    }
  }

  const int b = m0 >> 8;          // 128-row tile stays within one batch (T=256)
  const int t0 = m0 & 255;

  if (bx < 6) {
    // q / k : [B,H,T,D]
    unsigned short* outp = (bx < 3) ? q : k;
    const int cmbase = n0 - (bx < 3 ? 0 : 384);
#pragma unroll
    for (int ni = 0; ni < 4; ++ni) {
      int c = cmbase + wn + ni * 16 + l15;   // 0..383 within mat
      int h = c >> 6, d = c & 63;
#pragma unroll
      for (int mi = 0; mi < 4; ++mi)
#pragma unroll
        for (int r = 0; r < 4; ++r) {
          int t = t0 + wm + mi * 16 + quad * 4 + r;
          outp[(((size_t)b * HH + h) * TT + t) * DD + d] = f2bf(acc[mi][ni][r]);
        }
    }
  } else {
    // v : transpose to [B,H,D,T] via LDS bounce, one 64-col half (one head) per pass
#pragma unroll
    for (int pass = 0; pass < 2; ++pass) {
      __syncthreads();
      if ((wave >> 1) == pass) {
#pragma unroll
        for (int ni = 0; ni < 4; ++ni) {
          int cl = ni * 16 + l15;            // d within head
#pragma unroll
          for (int mi = 0; mi < 4; ++mi)
#pragma unroll
            for (int r = 0; r < 4; ++r) {
              int rloc = wm + mi * 16 + quad * 4 + r;   // t within tile
              bounce[cl * 136 + rloc] = f2bf(acc[mi][ni][r]);
            }
        }
      }
      __syncthreads();
      int h = (bx - 6) * 2 + pass;
      int d = tid >> 2;
      int tb = (tid & 3) * 32;
      unsigned short* vdst = v + (((size_t)b * HH + h) * DD + d) * TT + t0 + tb;
      const unsigned short* bsrc = &bounce[d * 136 + tb];
#pragma unroll
      for (int j = 0; j < 4; ++j)
        *(uint4*)(vdst + j * 8) = *(const uint4*)(bsrc + j * 8);
    }
  }
}

// ---------------------------------------------------------------------------
// Kernel 2: flash-style causal attention (unchanged from R1).
// ---------------------------------------------------------------------------
__global__ __launch_bounds__(256) void attn_kernel(const unsigned short* __restrict__ q,
                                                   const unsigned short* __restrict__ k,
                                                   const unsigned short* __restrict__ v,
                                                   unsigned short* __restrict__ att) {
  const int bh = blockIdx.x;
  const int q0 = blockIdx.y * 64;
  const int b = bh / HH, h = bh % HH;

  __shared__ unsigned short Qs[64 * 72];
  __shared__ unsigned short Ks[64 * 72];
  __shared__ unsigned short Vt[64 * 72];
  __shared__ unsigned short Ps[64 * 72];

  const int tid = threadIdx.x;
  const int wave = tid >> 6, lane = tid & 63;
  const int l15 = lane & 15, quad = lane >> 4;
  const int koff = quad * 8;

  {
    int r = tid >> 2, c = (tid & 3) * 16;
    const unsigned short* src = q + ((size_t)bh * TT + q0 + r) * DD + c;
    *(uint4*)&Qs[r * 72 + c]     = *(const uint4*)src;
    *(uint4*)&Qs[r * 72 + c + 8] = *(const uint4*)(src + 8);
  }

  f32x4 o_acc[4] = {{0.f,0.f,0.f,0.f},{0.f,0.f,0.f,0.f},{0.f,0.f,0.f,0.f},{0.f,0.f,0.f,0.f}};
  float m_run[4] = {-INFINITY, -INFINITY, -INFINITY, -INFINITY};
  float l_run[4] = {0.f, 0.f, 0.f, 0.f};
  const float scale = 0.125f;

  for (int j0 = 0; j0 <= q0; j0 += 64) {
    __syncthreads();
    {
      int r = tid >> 2, c = (tid & 3) * 16;
      const unsigned short* ks = k + ((size_t)bh * TT + j0 + r) * DD + c;
      *(uint4*)&Ks[r * 72 + c]     = *(const uint4*)ks;
      *(uint4*)&Ks[r * 72 + c + 8] = *(const uint4*)(ks + 8);
      const unsigned short* vs = v + ((size_t)bh * DD + r) * TT + j0 + c;
      *(uint4*)&Vt[r * 72 + c]     = *(const uint4*)vs;
      *(uint4*)&Vt[r * 72 + c + 8] = *(const uint4*)(vs + 8);
    }
    __syncthreads();

    f32x4 s_acc[4] = {{0.f,0.f,0.f,0.f},{0.f,0.f,0.f,0.f},{0.f,0.f,0.f,0.f},{0.f,0.f,0.f,0.f}};
#pragma unroll
    for (int kc = 0; kc < 2; ++kc) {
      bf16x8 a = *(const bf16x8*)&Qs[(wave * 16 + l15) * 72 + kc * 32 + koff];
#pragma unroll
      for (int ct = 0; ct < 4; ++ct) {
        bf16x8 bb = *(const bf16x8*)&Ks[(ct * 16 + l15) * 72 + kc * 32 + koff];
        s_acc[ct] = __builtin_amdgcn_mfma_f32_16x16x32_bf16(a, bb, s_acc[ct], 0, 0, 0);
      }
    }

    const bool diag = (j0 == q0);
    const int rowbase = q0 + wave * 16 + quad * 4;
#pragma unroll
    for (int r = 0; r < 4; ++r) {
      int qrow = rowbase + r;
      float sv[4];
#pragma unroll
      for (int ct = 0; ct < 4; ++ct) {
        float s = s_acc[ct][r] * scale;
        if (diag && (j0 + ct * 16 + l15) > qrow) s = -INFINITY;
        sv[ct] = s;
      }
      float mt = fmaxf(fmaxf(sv[0], sv[1]), fmaxf(sv[2], sv[3]));
      mt = fmaxf(mt, __shfl_xor(mt, 1));
      mt = fmaxf(mt, __shfl_xor(mt, 2));
      mt = fmaxf(mt, __shfl_xor(mt, 4));
      mt = fmaxf(mt, __shfl_xor(mt, 8));
      float mnew = fmaxf(m_run[r], mt);
      float alpha = __expf(m_run[r] - mnew);
      float psum = 0.f;
      int prow = (wave * 16 + quad * 4 + r) * 72;
#pragma unroll
      for (int ct = 0; ct < 4; ++ct) {
        float p = __expf(sv[ct] - mnew);
        psum += p;
        Ps[prow + ct * 16 + l15] = f2bf(p);
      }
      psum += __shfl_xor(psum, 1);
      psum += __shfl_xor(psum, 2);
      psum += __shfl_xor(psum, 4);
      psum += __shfl_xor(psum, 8);
      l_run[r] = l_run[r] * alpha + psum;
      m_run[r] = mnew;
#pragma unroll
      for (int dt = 0; dt < 4; ++dt) o_acc[dt][r] *= alpha;
    }

#pragma unroll
    for (int kc = 0; kc < 2; ++kc) {
      bf16x8 a = *(const bf16x8*)&Ps[(wave * 16 + l15) * 72 + kc * 32 + koff];
#pragma unroll
      for (int dt = 0; dt < 4; ++dt) {
        bf16x8 bb = *(const bf16x8*)&Vt[(dt * 16 + l15) * 72 + kc * 32 + koff];
        o_acc[dt] = __builtin_amdgcn_mfma_f32_16x16x32_bf16(a, bb, o_acc[dt], 0, 0, 0);
      }
    }
  }

#pragma unroll
  for (int dt = 0; dt < 4; ++dt) {
#pragma unroll
    for (int r = 0; r < 4; ++r) {
      int row = wave * 16 + quad * 4 + r;
      int t = q0 + row;
      int d = dt * 16 + l15;
      float o = o_acc[dt][r] / l_run[r];
      att[(((size_t)b * TT + t) * HH + h) * DD + d] = f2bf(o);
    }
  }
}

// ---------------------------------------------------------------------------
// Kernel 3: output projection  out[M,384] = att @ Wo + bo  (same GEMM template)
// ---------------------------------------------------------------------------
__global__ __launch_bounds__(256) void oproj128_kernel(const unsigned short* __restrict__ A,
                                                       const unsigned short* __restrict__ Wot,
                                                       const float* __restrict__ bo,
                                                       float* __restrict__ out) {
  const int n0 = blockIdx.x * 128;
  const int m0 = blockIdx.y * 128;

  __shared__ char smem[32768];
  unsigned short* As = (unsigned short*)smem;
  unsigned short* Bs = (unsigned short*)(smem + 16384);

  const int tid = threadIdx.x;
  const int wave = tid >> 6, lane = tid & 63;
  const int l15 = lane & 15, quad = lane >> 4;
  const int wm = (wave & 1) * 64, wn = (wave >> 1) * 64;
  const int xs = l15 & 7;

  f32x4 acc[4][4];
#pragma unroll
  for (int i = 0; i < 4; ++i)
#pragma unroll
    for (int j = 0; j < 4; ++j) acc[i][j] = (f32x4){0.f, 0.f, 0.f, 0.f};

  const int rl_base = wave * 32 + (lane >> 3);
  const int sb = lane & 7;

  for (int k0 = 0; k0 < EE; k0 += 64) {
    __syncthreads();
#pragma unroll
    for (int i = 0; i < 4; ++i) {
      int rl = rl_base + i * 8;
      int gcb = sb ^ (rl & 7);
      g2l16(A + (size_t)(m0 + rl) * EE + k0 + gcb * 8, &As[(wave * 32 + i * 8) * 64]);
    }
#pragma unroll
    for (int i = 0; i < 4; ++i) {
      int rl = rl_base + i * 8;
      int gcb = sb ^ (rl & 7);
      g2l16(Wot + (size_t)(n0 + rl) * EE + k0 + gcb * 8, &Bs[(wave * 32 + i * 8) * 64]);
    }
    __syncthreads();
#pragma unroll
    for (int kc = 0; kc < 2; ++kc) {
      bf16x8 af[4], bfr[4];
#pragma unroll
      for (int mi = 0; mi < 4; ++mi)
        af[mi] = *(const bf16x8*)&As[(wm + mi * 16 + l15) * 64 + ((kc * 4 + quad) ^ xs) * 8];
#pragma unroll
      for (int ni = 0; ni < 4; ++ni)
        bfr[ni] = *(const bf16x8*)&Bs[(wn + ni * 16 + l15) * 64 + ((kc * 4 + quad) ^ xs) * 8];
#pragma unroll
      for (int mi = 0; mi < 4; ++mi)
#pragma unroll
        for (int ni = 0; ni < 4; ++ni)
          acc[mi][ni] = __builtin_amdgcn_mfma_f32_16x16x32_bf16(af[mi], bfr[ni], acc[mi][ni], 0, 0, 0);
    }
  }

#pragma unroll
  for (int ni = 0; ni < 4; ++ni) {
    int c = n0 + wn + ni * 16 + l15;
    float bias = bo[c];
#pragma unroll
    for (int mi = 0; mi < 4; ++mi)
#pragma unroll
      for (int r = 0; r < 4; ++r) {
        int m = m0 + wm + mi * 16 + quad * 4 + r;
        out[(size_t)m * EE + c] = acc[mi][ni][r] + bias;
      }
  }
}

// ---------------------------------------------------------------------------
extern "C" void kernel_launch(void* const* d_in, const int* in_sizes, int n_in,
                              void* d_out, int out_size, void* d_ws, size_t ws_size,
                              hipStream_t stream) {
  const float* x  = (const float*)d_in[0];
  const float* Wq = (const float*)d_in[1];
  const float* Wk = (const float*)d_in[2];
  const float* Wv = (const float*)d_in[3];
  const float* Wo = (const float*)d_in[4];
  const float* bo = (const float*)d_in[5];
  float* out = (float*)d_out;

  char* ws = (char*)d_ws;
  const size_t SZ = (size_t)BB * TT * EE * 2;       // 48 MiB
  const size_t SQ = (size_t)BB * HH * TT * DD * 2;  // 48 MiB
  unsigned short* xb = (unsigned short*)ws;          // [B*T, E] bf16
  unsigned short* q  = (unsigned short*)(ws + SZ);
  unsigned short* k  = (unsigned short*)(ws + SZ + SQ);
  unsigned short* v  = (unsigned short*)(ws + SZ + 2 * SQ);
  unsigned short* Wt = (unsigned short*)(ws + SZ + 3 * SQ);  // [1536][384] bf16
  unsigned short* att = xb;  // xb dead after qkv; reuse for attention output

  int n4 = (BB * TT * EE) / 4;
  cvt_kernel<<<(n4 + 255) / 256, 256, 0, stream>>>(x, xb, n4);
  wprep_kernel<<<(1536 * 384 + 255) / 256, 256, 0, stream>>>(Wq, Wk, Wv, Wo, Wt);
  qkv128_kernel<<<dim3(9, (BB * TT) / 128), 256, 0, stream>>>(xb, Wt, q, k, v);
  attn_kernel<<<dim3(BB * HH, TT / 64), 256, 0, stream>>>(q, k, v, att);
  oproj128_kernel<<<dim3(3, (BB * TT) / 128), 256, 0, stream>>>(att, Wt + 1152 * 384, bo, out);
}